// Round 1
// baseline (1147.231 us; speedup 1.0000x reference)
//
#include <hip/hip_runtime.h>
#include <hip/hip_bf16.h>
#include <math.h>

#define SCAN_T 256
#define SCAN_ELEMS 2048

__device__ __forceinline__ float wave_reduce_max(float v) {
  #pragma unroll
  for (int off = 32; off; off >>= 1) v = fmaxf(v, __shfl_xor(v, off));
  return v;
}
__device__ __forceinline__ float wave_reduce_sum(float v) {
  #pragma unroll
  for (int off = 32; off; off >>= 1) v += __shfl_xor(v, off);
  return v;
}

// ---------------- CSR build ----------------

__global__ void k_count_deg(const int* __restrict__ ei, int* __restrict__ deg,
                            int E, int EE) {
  int e = blockIdx.x * blockDim.x + threadIdx.x;
  if (e >= EE) return;
  int d = (e < E) ? ei[E + e] : (e - E);   // dst row of edge_index, or self-loop
  atomicAdd(&deg[d], 1);
}

__global__ void k_scan_partial(const int* __restrict__ deg, int* __restrict__ partial, int n) {
  __shared__ int s[SCAN_T];
  int base = blockIdx.x * SCAN_ELEMS;
  int sum = 0;
  for (int i = threadIdx.x; i < SCAN_ELEMS; i += SCAN_T) {
    int idx = base + i;
    if (idx < n) sum += deg[idx];
  }
  s[threadIdx.x] = sum;
  __syncthreads();
  for (int off = SCAN_T / 2; off; off >>= 1) {
    if (threadIdx.x < off) s[threadIdx.x] += s[threadIdx.x + off];
    __syncthreads();
  }
  if (threadIdx.x == 0) partial[blockIdx.x] = s[0];
}

__global__ void k_scan_top(int* __restrict__ partial, int nb, int* __restrict__ total) {
  if (threadIdx.x == 0 && blockIdx.x == 0) {
    int run = 0;
    for (int i = 0; i < nb; i++) { int v = partial[i]; partial[i] = run; run += v; }
    *total = run;
  }
}

__global__ void k_scan_final(const int* __restrict__ deg, const int* __restrict__ partial,
                             int* __restrict__ rowptr, int n) {
  __shared__ int s[SCAN_T];
  int b = blockIdx.x, t = threadIdx.x;
  int base = b * SCAN_ELEMS + t * 8;
  int v[8]; int tot = 0;
  #pragma unroll
  for (int i = 0; i < 8; i++) { int idx = base + i; v[i] = (idx < n) ? deg[idx] : 0; tot += v[i]; }
  s[t] = tot;
  __syncthreads();
  for (int off = 1; off < SCAN_T; off <<= 1) {
    int add = (t >= off) ? s[t - off] : 0;
    __syncthreads();
    s[t] += add;
    __syncthreads();
  }
  int excl = (t ? s[t - 1] : 0) + partial[b];
  #pragma unroll
  for (int i = 0; i < 8; i++) { int idx = base + i; if (idx < n) rowptr[idx] = excl; excl += v[i]; }
}

__global__ void k_scatter(const int* __restrict__ ei, const int* __restrict__ rowptr,
                          int* __restrict__ fill, int* __restrict__ csr_src, int E, int EE) {
  int e = blockIdx.x * blockDim.x + threadIdx.x;
  if (e >= EE) return;
  int s, d;
  if (e < E) { s = ei[e]; d = ei[E + e]; } else { s = e - E; d = s; }
  int pos = rowptr[d] + atomicAdd(&fill[d], 1);
  csr_src[pos] = s;
}

// ---------------- GEMM h = x@W fused with alpha_s/alpha_d reductions ----------------

template <int FIN>
__global__ __launch_bounds__(256) void k_gemm(
    const float* __restrict__ x, const float* __restrict__ W,
    const float* __restrict__ avs, const float* __restrict__ avd,
    float* __restrict__ h, float* __restrict__ as_out, float* __restrict__ ad_out, int Nn) {
  __shared__ float Wl[FIN * 64];
  __shared__ float As[64], Ad[64];
  int t = threadIdx.x;
  for (int i = t; i < FIN * 64; i += 256) Wl[i] = W[i];
  if (t < 64) { As[t] = avs[t]; Ad[t] = avd[t]; }
  __syncthreads();
  int lane = t & 63, wid = t >> 6;
  int row = blockIdx.x * 4 + wid;
  if (row >= Nn) return;
  float xv[FIN / 64];
  #pragma unroll
  for (int i = 0; i < FIN / 64; i++) xv[i] = x[(size_t)row * FIN + i * 64 + lane];
  float acc = 0.f;
  #pragma unroll
  for (int i = 0; i < FIN / 64; i++) {
    #pragma unroll
    for (int k = 0; k < 64; k++) {
      float xb = __shfl(xv[i], k);
      acc = fmaf(xb, Wl[(i * 64 + k) * 64 + lane], acc);
    }
  }
  h[(size_t)row * 64 + lane] = acc;
  float vs = wave_reduce_sum(acc * As[lane]);
  float vd = wave_reduce_sum(acc * Ad[lane]);
  if (lane == 0) { as_out[row] = vs; ad_out[row] = vd; }
}

// ---------------- per-dst-node softmax aggregation ----------------
// one wave per destination node; lane = feature dim in the gather phase

__global__ __launch_bounds__(256) void k_agg(
    const int* __restrict__ rowptr, const int* __restrict__ csr_src,
    const float* __restrict__ h, const float* __restrict__ as_,
    const float* __restrict__ ad_, const float* __restrict__ bias,
    float* __restrict__ out, int Nn) {
  int t = threadIdx.x, lane = t & 63, wid = t >> 6;
  int n = blockIdx.x * 4 + wid;
  if (n >= Nn) return;
  int r0 = rowptr[n], r1 = rowptr[n + 1];
  float ad = ad_[n];
  // phase A: edge-parallel max of leaky_relu scores
  float m = -3.4e38f;
  for (int j = r0 + lane; j < r1; j += 64) {
    float e = as_[csr_src[j]] + ad;
    e = (e >= 0.f) ? e : 0.2f * e;
    m = fmaxf(m, e);
  }
  m = wave_reduce_max(m);
  // phase B: serial over edges, lane = feature dim; coalesced 256B gathers of h[src]
  float acc = 0.f, ssum = 0.f;
  for (int j = r0; j < r1; ++j) {
    int src = csr_src[j];
    float e = as_[src] + ad;
    e = (e >= 0.f) ? e : 0.2f * e;
    float p = __expf(e - m);
    ssum += p;
    acc = fmaf(p, h[(size_t)src * 64 + lane], acc);
  }
  float o = acc / (ssum + 1e-16f) + bias[lane];
  out[(size_t)n * 64 + lane] = fmaxf(o, 0.f);  // relu (all 3 layers)
}

// ---------------- final linear + sigmoid ----------------

__global__ __launch_bounds__(256) void k_final(
    const float* __restrict__ h, const float* __restrict__ Wl,
    const float* __restrict__ bl, float* __restrict__ out, int Nn) {
  int t = threadIdx.x, lane = t & 63, wid = t >> 6;
  int n = blockIdx.x * 4 + wid;
  if (n >= Nn) return;
  float v = h[(size_t)n * 64 + lane] * Wl[lane];
  v = wave_reduce_sum(v);
  if (lane == 0) {
    float z = v + bl[0];
    out[n] = 1.f / (1.f + __expf(-z));
  }
}

extern "C" void kernel_launch(void* const* d_in, const int* in_sizes, int n_in,
                              void* d_out, int out_size, void* d_ws, size_t ws_size,
                              hipStream_t stream) {
  const float* x   = (const float*)d_in[0];
  const int*   ei  = (const int*)d_in[1];
  const float* W1  = (const float*)d_in[2];
  const float* a1s = (const float*)d_in[3];
  const float* a1d = (const float*)d_in[4];
  const float* b1  = (const float*)d_in[5];
  const float* W2  = (const float*)d_in[6];
  const float* a2s = (const float*)d_in[7];
  const float* a2d = (const float*)d_in[8];
  const float* b2  = (const float*)d_in[9];
  const float* W3  = (const float*)d_in[10];
  const float* a3s = (const float*)d_in[11];
  const float* a3d = (const float*)d_in[12];
  const float* b3  = (const float*)d_in[13];
  const float* Wl  = (const float*)d_in[14];
  const float* bl  = (const float*)d_in[15];

  const int N  = in_sizes[0] / 128;
  const int E  = in_sizes[1] / 2;
  const int EE = E + N;

  char* p = (char*)d_ws;
  auto alloc = [&](size_t bytes) { char* r = p; p += (bytes + 255) & ~(size_t)255; return r; };
  int*   deg     = (int*)alloc((size_t)N * 4);
  int*   fill    = (int*)alloc((size_t)N * 4);
  int*   rowptr  = (int*)alloc((size_t)(N + 1) * 4);
  int*   partial = (int*)alloc(256 * 4);
  int*   csr_src = (int*)alloc((size_t)EE * 4);
  float* hbuf    = (float*)alloc((size_t)N * 64 * 4);
  float* obuf    = (float*)alloc((size_t)N * 64 * 4);
  float* as_     = (float*)alloc((size_t)N * 4);
  float* ad_     = (float*)alloc((size_t)N * 4);

  hipMemsetAsync(deg,  0, (size_t)N * 4, stream);
  hipMemsetAsync(fill, 0, (size_t)N * 4, stream);

  int eb = (EE + 255) / 256;
  k_count_deg<<<eb, 256, 0, stream>>>(ei, deg, E, EE);
  int nchunks = (N + SCAN_ELEMS - 1) / SCAN_ELEMS;
  k_scan_partial<<<nchunks, SCAN_T, 0, stream>>>(deg, partial, N);
  k_scan_top<<<1, 64, 0, stream>>>(partial, nchunks, rowptr + N);
  k_scan_final<<<nchunks, SCAN_T, 0, stream>>>(deg, partial, rowptr, N);
  k_scatter<<<eb, 256, 0, stream>>>(ei, rowptr, fill, csr_src, E, EE);

  int nb = (N + 3) / 4;
  // layer 1
  k_gemm<128><<<nb, 256, 0, stream>>>(x, W1, a1s, a1d, hbuf, as_, ad_, N);
  k_agg<<<nb, 256, 0, stream>>>(rowptr, csr_src, hbuf, as_, ad_, b1, obuf, N);
  // layer 2
  k_gemm<64><<<nb, 256, 0, stream>>>(obuf, W2, a2s, a2d, hbuf, as_, ad_, N);
  k_agg<<<nb, 256, 0, stream>>>(rowptr, csr_src, hbuf, as_, ad_, b2, obuf, N);
  // layer 3
  k_gemm<64><<<nb, 256, 0, stream>>>(obuf, W3, a3s, a3d, hbuf, as_, ad_, N);
  k_agg<<<nb, 256, 0, stream>>>(rowptr, csr_src, hbuf, as_, ad_, b3, obuf, N);
  // readout
  k_final<<<nb, 256, 0, stream>>>(obuf, Wl, bl, (float*)d_out, N);
}